// Round 1
// baseline (146.908 us; speedup 1.0000x reference)
//
#include <hip/hip_runtime.h>
#include <math.h>
#include <cstddef>

// Shapes fixed by setup_inputs()
#define B_  16
#define T2_ 2048
#define T1_ 512
#define F_  128

constexpr float DELTA_C = 10.0f;
constexpr float EPS_C   = 1e-8f;
constexpr float THRESH_C = 0.9f;
constexpr float STEEP_C  = 10.0f;

__device__ __forceinline__ float wave_reduce_sum(float v) {
    for (int off = 32; off > 0; off >>= 1) v += __shfl_xor(v, off, 64);
    return v;
}

// --- K1: activity[b,t] = sigmoid(10*(0.9 - cos(mels[t-1], mels[t]))) * am, act[.,0]=am
__global__ __launch_bounds__(256) void act_kernel(const float* __restrict__ mels,
                                                  const int* __restrict__ mel_mask,
                                                  float* __restrict__ act) {
    int wid  = (int)((blockIdx.x * blockDim.x + threadIdx.x) >> 6);
    int lane = threadIdx.x & 63;
    if (wid >= B_ * T2_) return;
    int t = wid % T2_;
    float a_val;
    if (t == 0) {
        a_val = 1.0f;
    } else {
        const float2* r0 = (const float2*)(mels + (size_t)(wid - 1) * F_);
        const float2* r1 = (const float2*)(mels + (size_t)wid * F_);
        float2 x = r0[lane];
        float2 y = r1[lane];
        float d  = x.x * y.x + x.y * y.y;
        float n0 = x.x * x.x + x.y * x.y;
        float n1 = y.x * y.x + y.y * y.y;
        for (int off = 32; off > 0; off >>= 1) {
            d  += __shfl_xor(d, off, 64);
            n0 += __shfl_xor(n0, off, 64);
            n1 += __shfl_xor(n1, off, 64);
        }
        float cs = d / (fmaxf(sqrtf(n0), 1e-12f) * fmaxf(sqrtf(n1), 1e-12f));
        a_val = 1.0f / (1.0f + __expf(-STEEP_C * (THRESH_C - cs)));
    }
    if (lane == 0) act[wid] = a_val * (float)mel_mask[wid];
}

// --- K2: imv_proposal[b,t] = sum_s alpha[b,t,s] * s   (one wave per row of 512)
__global__ __launch_bounds__(256) void prop_kernel(const float* __restrict__ alpha,
                                                   float* __restrict__ prop) {
    int wid  = (int)((blockIdx.x * blockDim.x + threadIdx.x) >> 6);
    int lane = threadIdx.x & 63;
    if (wid >= B_ * T2_) return;
    const float4* row = (const float4*)(alpha + (size_t)wid * T1_);
    float4 v0 = row[lane * 2];
    float4 v1 = row[lane * 2 + 1];
    float s0 = (float)(lane * 8);
    float sum = v0.x * s0 + v0.y * (s0 + 1.0f) + v0.z * (s0 + 2.0f) + v0.w * (s0 + 3.0f)
              + v1.x * (s0 + 4.0f) + v1.y * (s0 + 5.0f) + v1.z * (s0 + 6.0f) + v1.w * (s0 + 7.0f);
    sum = wave_reduce_sum(sum);
    if (lane == 0) prop[wid] = sum;
}

// --- K3: per batch: eff_delta -> cumsum -> rescale -> imv; softmax denominator Z
__global__ __launch_bounds__(256) void scan_kernel(const float* __restrict__ prop,
                                                   const float* __restrict__ act,
                                                   const int* __restrict__ mel_mask,
                                                   const int* __restrict__ text_mask,
                                                   float* __restrict__ imv_out,
                                                   float* __restrict__ Zout) {
    int b   = blockIdx.x;
    int tid = threadIdx.x;  // 256 threads, 8 elements each
    __shared__ float s_imv[T2_];
    __shared__ float s_part[256];
    __shared__ int s_am, s_tm;
    if (tid == 0) { s_am = 0; s_tm = 0; }
    __syncthreads();

    const float* pr = prop + (size_t)b * T2_;
    const float* ac = act + (size_t)b * T2_;
    const int*   mm = mel_mask + (size_t)b * T2_;
    const int*   tm = text_mask + (size_t)b * T1_;

    float e[8];
    int t0 = tid * 8;
    int am_local = 0;
    float run = 0.0f;
    for (int i = 0; i < 8; i++) {
        int t = t0 + i;
        float d = (t == 0) ? 0.0f : (pr[t] - pr[t - 1]) * ac[t];
        d = fminf(fmaxf(d, 0.0f), 1.0f);
        run += d;
        e[i] = run;
        am_local += mm[t];
    }
    s_part[tid] = run;
    atomicAdd(&s_am, am_local);
    atomicAdd(&s_tm, tm[tid] + tm[tid + 256]);
    __syncthreads();

    // Hillis-Steele inclusive scan over 256 partials
    for (int off = 1; off < 256; off <<= 1) {
        float u = (tid >= off) ? s_part[tid - off] : 0.0f;
        __syncthreads();
        s_part[tid] += u;
        __syncthreads();
    }
    float excl = (tid == 0) ? 0.0f : s_part[tid - 1];
    for (int i = 0; i < 8; i++) {
        int t = t0 + i;
        s_imv[t] = (e[i] + excl) * (float)mm[t];
    }
    __syncthreads();

    int last_idx = max(s_am - 1, 0);
    float last_val = fmaxf(s_imv[last_idx], 1e-6f);
    float scale = fmaxf((float)s_tm - 1.0f, 0.0f) / last_val;

    for (int i = 0; i < 8; i++) {
        int t = t0 + i;
        float v = s_imv[t] * scale * (float)mm[t];
        imv_out[(size_t)b * T2_ + t] = v;
        // softmax denominator: 6-term band around floor(v); terms beyond are <4e-18 relative
        int c = (int)floorf(v);
        float Z = 0.0f;
        for (int s = c - 2; s <= c + 3; s++) {
            if (s >= 0 && s < T1_ && tm[s]) {
                float dd = v - (float)s;
                Z += __expf(-DELTA_C * dd * dd);
            }
        }
        Zout[(size_t)b * T2_ + t] = fmaxf(Z, 1e-30f);
    }
}

// --- K4: one wave per (b,s): banded column sum over t with |imv[t]-s| <= 3
__global__ __launch_bounds__(256) void pool_kernel(const float* __restrict__ mels,
                                                   const int* __restrict__ mel_mask,
                                                   const int* __restrict__ text_mask,
                                                   const float* __restrict__ imv,
                                                   const float* __restrict__ Z,
                                                   float* __restrict__ aligned,
                                                   float* __restrict__ dur) {
    int wid  = (int)((blockIdx.x * blockDim.x + threadIdx.x) >> 6);
    int lane = threadIdx.x & 63;
    if (wid >= B_ * T1_) return;
    int b = wid / T1_, s = wid % T1_;
    const float* iv = imv + (size_t)b * T2_;

    // imv is monotone nondecreasing in t -> contiguous band via binary search
    float lo_v = (float)s - 3.0f, hi_v = (float)s + 3.0f;
    int lo = 0, hi = T2_;
    while (lo < hi) { int mid = (lo + hi) >> 1; if (iv[mid] >= lo_v) hi = mid; else lo = mid + 1; }
    int t_lo = lo;
    lo = t_lo; hi = T2_;
    while (lo < hi) { int mid = (lo + hi) >> 1; if (iv[mid] > hi_v) hi = mid; else lo = mid + 1; }
    int t_hi = lo;

    const float* zz = Z + (size_t)b * T2_;
    const int*   mm = mel_mask + (size_t)b * T2_;
    float2 acc = {0.0f, 0.0f};
    float gsum = 0.0f;
    for (int t = t_lo; t < t_hi; t++) {
        float d = iv[t] - (float)s;
        float g = (float)mm[t] * __expf(-DELTA_C * d * d) / zz[t];
        gsum += g;
        float2 m = ((const float2*)(mels + ((size_t)b * T2_ + t) * F_))[lane];
        acc.x += g * m.x;
        acc.y += g * m.y;
    }
    float tmv = (float)text_mask[(size_t)b * T1_ + s];
    float inv = tmv / (gsum + EPS_C);
    float2 outv = {acc.x * inv, acc.y * inv};
    ((float2*)(aligned + ((size_t)b * T1_ + s) * F_))[lane] = outv;
    if (lane == 0) dur[(size_t)b * T1_ + s] = gsum * tmv;
}

extern "C" void kernel_launch(void* const* d_in, const int* in_sizes, int n_in,
                              void* d_out, int out_size, void* d_ws, size_t ws_size,
                              hipStream_t stream) {
    const float* mels      = (const float*)d_in[0];
    const float* alpha     = (const float*)d_in[1];
    const int*   mel_mask  = (const int*)d_in[2];
    const int*   text_mask = (const int*)d_in[3];

    float* out     = (float*)d_out;
    float* aligned = out;                                   // B*T1*F
    float* dur     = out + (size_t)B_ * T1_ * F_;           // B*T1
    float* imv     = dur + (size_t)B_ * T1_;                // B*T2

    float* ws   = (float*)d_ws;                             // needs 3*B*T2 floats = 384 KB
    float* act  = ws;
    float* prop = ws + (size_t)B_ * T2_;
    float* Z    = ws + 2 * (size_t)B_ * T2_;

    dim3 blk(256);
    act_kernel <<<(B_ * T2_) / 4, blk, 0, stream>>>(mels, mel_mask, act);
    prop_kernel<<<(B_ * T2_) / 4, blk, 0, stream>>>(alpha, prop);
    scan_kernel<<<B_, blk, 0, stream>>>(prop, act, mel_mask, text_mask, imv, Z);
    pool_kernel<<<(B_ * T1_) / 4, blk, 0, stream>>>(mels, mel_mask, text_mask, imv, Z, aligned, dur);
}

// Round 2
// 134.297 us; speedup vs baseline: 1.0939x; 1.0939x over previous
//
#include <hip/hip_runtime.h>
#include <math.h>
#include <cstddef>

// Shapes fixed by setup_inputs()
#define B_  16
#define T2_ 2048
#define T1_ 512
#define F_  128

constexpr float DELTA_C  = 10.0f;
constexpr float EPS_C    = 1e-8f;
constexpr float THRESH_C = 0.9f;
constexpr float STEEP_C  = 10.0f;

// --- K1 (fused): activity + imv_proposal, one wave per (b,t)
// alpha row loads fully coalesced: row[lane] (first 1KiB), row[lane+64] (second 1KiB)
__global__ __launch_bounds__(256) void actprop_kernel(const float* __restrict__ mels,
                                                      const float* __restrict__ alpha,
                                                      const int* __restrict__ mel_mask,
                                                      float* __restrict__ act,
                                                      float* __restrict__ prop) {
    int wid  = (int)((blockIdx.x * blockDim.x + threadIdx.x) >> 6);
    int lane = threadIdx.x & 63;
    if (wid >= B_ * T2_) return;
    int t = wid % T2_;

    const float4* row = (const float4*)(alpha + (size_t)wid * T1_);
    float4 v0 = row[lane];
    float4 v1 = row[lane + 64];

    float d = 0.f, n0 = 0.f, n1 = 0.f;
    if (t > 0) {
        float2 x = ((const float2*)(mels + (size_t)(wid - 1) * F_))[lane];
        float2 y = ((const float2*)(mels + (size_t)wid * F_))[lane];
        d  = x.x * y.x + x.y * y.y;
        n0 = x.x * x.x + x.y * x.y;
        n1 = y.x * y.x + y.y * y.y;
    }

    float fL = (float)(lane * 4);
    float psum = v0.x * fL + v0.y * (fL + 1.f) + v0.z * (fL + 2.f) + v0.w * (fL + 3.f)
               + v1.x * (fL + 256.f) + v1.y * (fL + 257.f) + v1.z * (fL + 258.f) + v1.w * (fL + 259.f);

    // 4 independent reduction chains -> ILP across the shuffle latency
    for (int off = 32; off > 0; off >>= 1) {
        psum += __shfl_xor(psum, off, 64);
        d    += __shfl_xor(d,    off, 64);
        n0   += __shfl_xor(n0,   off, 64);
        n1   += __shfl_xor(n1,   off, 64);
    }

    if (lane == 0) {
        float a_val;
        if (t == 0) {
            a_val = 1.0f;
        } else {
            float cs = d / (fmaxf(sqrtf(n0), 1e-12f) * fmaxf(sqrtf(n1), 1e-12f));
            a_val = 1.0f / (1.0f + __expf(-STEEP_C * (THRESH_C - cs)));
        }
        act[wid]  = a_val * (float)mel_mask[wid];
        prop[wid] = psum;
    }
}

// --- K2: per batch: eff_delta -> cumsum -> rescale -> imv; packed {key, am/Z} for pool
__global__ __launch_bounds__(256) void scan_kernel(const float* __restrict__ prop,
                                                   const float* __restrict__ act,
                                                   const int* __restrict__ mel_mask,
                                                   const int* __restrict__ text_mask,
                                                   float* __restrict__ imv_out,
                                                   float2* __restrict__ packed) {
    int b    = blockIdx.x;
    int tid  = threadIdx.x;            // 256 threads, 8 elements each
    int wave = tid >> 6, lane = tid & 63;
    __shared__ float s_imv[T2_];
    __shared__ float s_part[256];
    __shared__ int   s_am4[4], s_tm4[4];

    const float* pr = prop + (size_t)b * T2_;
    const float* ac = act  + (size_t)b * T2_;
    const int*   mm = mel_mask  + (size_t)b * T2_;
    const int*   tm = text_mask + (size_t)b * T1_;

    float e[8];
    int t0 = tid * 8;
    int am_local = 0;
    float run = 0.0f;
    for (int i = 0; i < 8; i++) {
        int t = t0 + i;
        float d = (t == 0) ? 0.0f : (pr[t] - pr[t - 1]) * ac[t];
        d = fminf(fmaxf(d, 0.0f), 1.0f);
        run += d;
        e[i] = run;
        am_local += mm[t];
    }
    int tm_local = tm[tid] + tm[tid + 256];
    for (int off = 32; off > 0; off >>= 1) {
        am_local += __shfl_xor(am_local, off, 64);
        tm_local += __shfl_xor(tm_local, off, 64);
    }
    if (lane == 0) { s_am4[wave] = am_local; s_tm4[wave] = tm_local; }
    s_part[tid] = run;
    __syncthreads();

    // Hillis-Steele inclusive scan over 256 partials
    for (int off = 1; off < 256; off <<= 1) {
        float u = (tid >= off) ? s_part[tid - off] : 0.0f;
        __syncthreads();
        s_part[tid] += u;
        __syncthreads();
    }
    float excl = (tid == 0) ? 0.0f : s_part[tid - 1];
    for (int i = 0; i < 8; i++) {
        int t = t0 + i;
        s_imv[t] = (e[i] + excl) * (float)mm[t];
    }
    __syncthreads();

    int am_total = s_am4[0] + s_am4[1] + s_am4[2] + s_am4[3];
    int tm_total = s_tm4[0] + s_tm4[1] + s_tm4[2] + s_tm4[3];
    int last_idx = max(am_total - 1, 0);
    float last_val = fmaxf(s_imv[last_idx], 1e-6f);
    float scale = fmaxf((float)tm_total - 1.0f, 0.0f) / last_val;

    for (int i = 0; i < 8; i++) {
        int t = t0 + i;
        int valid = mm[t];
        float v = s_imv[t] * scale * (float)valid;
        imv_out[(size_t)b * T2_ + t] = v;
        // softmax denominator: 6-term band around floor(v); terms beyond are <4e-18 relative
        int c = (int)floorf(v);
        float Z = 0.0f;
        for (int s = c - 2; s <= c + 3; s++) {
            if (s >= 0 && s < T1_ && tm[s]) {
                float dd = v - (float)s;
                Z += __expf(-DELTA_C * dd * dd);
            }
        }
        Z = fmaxf(Z, 1e-30f);
        float2 pk;
        pk.x = valid ? v : 3.0e4f;           // keep search key monotone past masked tail
        pk.y = valid ? (1.0f / Z) : 0.0f;    // r = am/Z
        packed[(size_t)b * T2_ + t] = pk;
    }
}

// --- K3: one wave per (b,s): banded column sum over t with |imv[t]-s| <= 3
__global__ __launch_bounds__(256) void pool_kernel(const float* __restrict__ mels,
                                                   const int* __restrict__ text_mask,
                                                   const float2* __restrict__ packed,
                                                   float* __restrict__ aligned,
                                                   float* __restrict__ dur) {
    int wid  = (int)((blockIdx.x * blockDim.x + threadIdx.x) >> 6);
    int lane = threadIdx.x & 63;
    if (wid >= B_ * T1_) return;
    int b = wid / T1_, s = wid % T1_;
    const float2* pk   = packed + (size_t)b * T2_;
    const float2* mel2 = (const float2*)(mels + (size_t)b * T2_ * F_);

    float fs = (float)s;
    // imv keys are monotone nondecreasing -> contiguous band via binary search
    float lo_v = fs - 3.0f, hi_v = fs + 3.0f;
    int lo = 0, hi = T2_;
    while (lo < hi) { int mid = (lo + hi) >> 1; if (pk[mid].x >= lo_v) hi = mid; else lo = mid + 1; }
    int t_lo = lo;
    hi = T2_;
    while (lo < hi) { int mid = (lo + hi) >> 1; if (pk[mid].x > hi_v) hi = mid; else lo = mid + 1; }
    int t_hi = lo;

    float ax = 0.0f, ay = 0.0f, gsum = 0.0f;
    int t = t_lo;
    // unrolled x4: batch independent loads so latency pipelines
    for (; t + 4 <= t_hi; t += 4) {
        float2 p0 = pk[t], p1 = pk[t + 1], p2 = pk[t + 2], p3 = pk[t + 3];
        float2 m0 = mel2[(size_t)(t    ) * 64 + lane];
        float2 m1 = mel2[(size_t)(t + 1) * 64 + lane];
        float2 m2 = mel2[(size_t)(t + 2) * 64 + lane];
        float2 m3 = mel2[(size_t)(t + 3) * 64 + lane];
        float d0 = p0.x - fs, d1 = p1.x - fs, d2 = p2.x - fs, d3 = p3.x - fs;
        float g0 = __expf(-DELTA_C * d0 * d0) * p0.y;
        float g1 = __expf(-DELTA_C * d1 * d1) * p1.y;
        float g2 = __expf(-DELTA_C * d2 * d2) * p2.y;
        float g3 = __expf(-DELTA_C * d3 * d3) * p3.y;
        gsum += (g0 + g1) + (g2 + g3);
        ax += g0 * m0.x + g1 * m1.x + g2 * m2.x + g3 * m3.x;
        ay += g0 * m0.y + g1 * m1.y + g2 * m2.y + g3 * m3.y;
    }
    for (; t < t_hi; t++) {
        float2 p = pk[t];
        float2 m = mel2[(size_t)t * 64 + lane];
        float dd = p.x - fs;
        float g  = __expf(-DELTA_C * dd * dd) * p.y;
        gsum += g;
        ax += g * m.x;
        ay += g * m.y;
    }

    float tmv = (float)text_mask[(size_t)b * T1_ + s];
    float inv = tmv / (gsum + EPS_C);
    float2 outv = {ax * inv, ay * inv};
    ((float2*)(aligned + ((size_t)b * T1_ + s) * F_))[lane] = outv;
    if (lane == 0) dur[(size_t)b * T1_ + s] = gsum * tmv;
}

extern "C" void kernel_launch(void* const* d_in, const int* in_sizes, int n_in,
                              void* d_out, int out_size, void* d_ws, size_t ws_size,
                              hipStream_t stream) {
    const float* mels      = (const float*)d_in[0];
    const float* alpha     = (const float*)d_in[1];
    const int*   mel_mask  = (const int*)d_in[2];
    const int*   text_mask = (const int*)d_in[3];

    float* out     = (float*)d_out;
    float* aligned = out;                                   // B*T1*F
    float* dur     = out + (size_t)B_ * T1_ * F_;           // B*T1
    float* imv     = dur + (size_t)B_ * T1_;                // B*T2

    float*  ws     = (float*)d_ws;                          // needs 4*B*T2 floats = 512 KB
    float*  act    = ws;
    float*  prop   = ws + (size_t)B_ * T2_;
    float2* packed = (float2*)(ws + 2 * (size_t)B_ * T2_);

    dim3 blk(256);
    actprop_kernel<<<(B_ * T2_) / 4, blk, 0, stream>>>(mels, alpha, mel_mask, act, prop);
    scan_kernel   <<<B_,            blk, 0, stream>>>(prop, act, mel_mask, text_mask, imv, packed);
    pool_kernel   <<<(B_ * T1_) / 4, blk, 0, stream>>>(mels, text_mask, packed, aligned, dur);
}

// Round 3
// 133.083 us; speedup vs baseline: 1.1039x; 1.0091x over previous
//
#include <hip/hip_runtime.h>
#include <math.h>
#include <cstddef>

// Shapes fixed by setup_inputs()
#define B_  16
#define T2_ 2048
#define T1_ 512
#define F_  128

constexpr float DELTA_C  = 10.0f;
constexpr float EPS_C    = 1e-8f;
constexpr float THRESH_C = 0.9f;
constexpr float STEEP_C  = 10.0f;

typedef float f4v __attribute__((ext_vector_type(4)));

// --- K1 (fused): activity + imv_proposal, one wave per (b,t)
// alpha is streamed exactly once -> nontemporal loads keep it out of L2
// (mels stays cached: re-read by pool_kernel).
__global__ __launch_bounds__(256) void actprop_kernel(const float* __restrict__ mels,
                                                      const float* __restrict__ alpha,
                                                      const int* __restrict__ mel_mask,
                                                      float* __restrict__ act,
                                                      float* __restrict__ prop) {
    int wid  = (int)((blockIdx.x * blockDim.x + threadIdx.x) >> 6);
    int lane = threadIdx.x & 63;
    if (wid >= B_ * T2_) return;
    int t = wid % T2_;

    const f4v* row = (const f4v*)(alpha + (size_t)wid * T1_);
    f4v v0 = __builtin_nontemporal_load(&row[lane]);        // first 1 KiB, coalesced
    f4v v1 = __builtin_nontemporal_load(&row[lane + 64]);   // second 1 KiB

    float d = 0.f, n0 = 0.f, n1 = 0.f;
    if (t > 0) {
        float2 x = ((const float2*)(mels + (size_t)(wid - 1) * F_))[lane];
        float2 y = ((const float2*)(mels + (size_t)wid * F_))[lane];
        d  = x.x * y.x + x.y * y.y;
        n0 = x.x * x.x + x.y * x.y;
        n1 = y.x * y.x + y.y * y.y;
    }

    float fL = (float)(lane * 4);
    float psum = v0.x * fL + v0.y * (fL + 1.f) + v0.z * (fL + 2.f) + v0.w * (fL + 3.f)
               + v1.x * (fL + 256.f) + v1.y * (fL + 257.f) + v1.z * (fL + 258.f) + v1.w * (fL + 259.f);

    // 4 independent reduction chains -> ILP across the shuffle latency
    for (int off = 32; off > 0; off >>= 1) {
        psum += __shfl_xor(psum, off, 64);
        d    += __shfl_xor(d,    off, 64);
        n0   += __shfl_xor(n0,   off, 64);
        n1   += __shfl_xor(n1,   off, 64);
    }

    if (lane == 0) {
        float a_val;
        if (t == 0) {
            a_val = 1.0f;
        } else {
            float cs = d / (fmaxf(sqrtf(n0), 1e-12f) * fmaxf(sqrtf(n1), 1e-12f));
            a_val = 1.0f / (1.0f + __expf(-STEEP_C * (THRESH_C - cs)));
        }
        act[wid]  = a_val * (float)mel_mask[wid];
        prop[wid] = psum;
    }
}

// --- K2: per batch: eff_delta -> wave-shuffle scan -> rescale -> imv,
//     packed {key, am/Z}, and per-phoneme band bounds via LDS binary search.
__global__ __launch_bounds__(256) void scan_kernel(const float* __restrict__ prop,
                                                   const float* __restrict__ act,
                                                   const int* __restrict__ mel_mask,
                                                   const int* __restrict__ text_mask,
                                                   float* __restrict__ imv_out,
                                                   float2* __restrict__ packed,
                                                   int2* __restrict__ bounds) {
    int b    = blockIdx.x;
    int tid  = threadIdx.x;            // 256 threads, 8 t's each
    int wave = tid >> 6, lane = tid & 63;
    __shared__ float s_imv[T2_];       // later overwritten with search keys
    __shared__ float s_wsum[4];
    __shared__ int   s_am4[4], s_tm4[4];
    __shared__ int   s_tm[T1_];

    const float* pr = prop + (size_t)b * T2_;
    const float* ac = act  + (size_t)b * T2_;
    const int*   mm = mel_mask  + (size_t)b * T2_;
    const int*   tm = text_mask + (size_t)b * T1_;

    int tmv0 = tm[tid], tmv1 = tm[tid + 256];
    s_tm[tid] = tmv0; s_tm[tid + 256] = tmv1;

    float e[8];
    int   mmv[8];
    int t0 = tid * 8;
    int am_local = 0;
    float run = 0.0f;
    for (int i = 0; i < 8; i++) {
        int t = t0 + i;
        float d = (t == 0) ? 0.0f : (pr[t] - pr[t - 1]) * ac[t];
        d = fminf(fmaxf(d, 0.0f), 1.0f);
        run += d;
        e[i] = run;
        mmv[i] = mm[t];
        am_local += mmv[i];
    }
    int tm_local = tmv0 + tmv1;
    for (int off = 32; off > 0; off >>= 1) {
        am_local += __shfl_xor(am_local, off, 64);
        tm_local += __shfl_xor(tm_local, off, 64);
    }
    if (lane == 0) { s_am4[wave] = am_local; s_tm4[wave] = tm_local; }

    // wave-level inclusive scan of per-thread totals
    float v = run;
    for (int off = 1; off < 64; off <<= 1) {
        float u = __shfl_up(v, off, 64);
        if (lane >= off) v += u;
    }
    if (lane == 63) s_wsum[wave] = v;
    __syncthreads();                                    // B1

    float woff = 0.0f;
    for (int w = 0; w < 4; w++) woff += (w < wave) ? s_wsum[w] : 0.0f;
    float excl = woff + v - run;
    for (int i = 0; i < 8; i++) {
        int t = t0 + i;
        s_imv[t] = (e[i] + excl) * (float)mmv[i];
    }
    __syncthreads();                                    // B2

    int am_total = s_am4[0] + s_am4[1] + s_am4[2] + s_am4[3];
    int tm_total = s_tm4[0] + s_tm4[1] + s_tm4[2] + s_tm4[3];
    int last_idx = max(am_total - 1, 0);
    float last_val = fmaxf(s_imv[last_idx], 1e-6f);
    float scale = fmaxf((float)tm_total - 1.0f, 0.0f) / last_val;
    __syncthreads();                                    // B3 (everyone read last_val)

    for (int i = 0; i < 8; i++) {
        int t = t0 + i;
        int valid = mmv[i];
        float vv = s_imv[t] * scale * (float)valid;
        imv_out[(size_t)b * T2_ + t] = vv;
        // softmax denominator: 6-term band around floor(vv); excluded terms < 1e-39
        int c = (int)floorf(vv);
        float Z = 0.0f;
        for (int s = c - 2; s <= c + 3; s++) {
            if (s >= 0 && s < T1_ && s_tm[s]) {
                float dd = vv - (float)s;
                Z += __expf(-DELTA_C * dd * dd);
            }
        }
        Z = fmaxf(Z, 1e-30f);
        float key = valid ? vv : 3.0e4f;                // monotone past masked tail
        float2 pk = {key, valid ? (1.0f / Z) : 0.0f};   // r = am/Z
        packed[(size_t)b * T2_ + t] = pk;
        s_imv[t] = key;                                 // key array for searches
    }
    __syncthreads();                                    // B4

    // per-phoneme band bounds: start = lower_bound(key >= s-3), end = upper_bound(key > s+3)
    for (int k = 0; k < 2; k++) {
        int s = tid + k * 256;
        float lov = (float)s - 3.0f, hiv = (float)s + 3.0f;
        int lo = 0, hi = T2_;
        while (lo < hi) { int mid = (lo + hi) >> 1; if (s_imv[mid] >= lov) hi = mid; else lo = mid + 1; }
        int st = lo;
        hi = T2_;
        while (lo < hi) { int mid = (lo + hi) >> 1; if (s_imv[mid] > hiv) hi = mid; else lo = mid + 1; }
        int2 be = {st, lo};
        bounds[(size_t)b * T1_ + s] = be;
    }
}

// --- K3: one wave per 2 adjacent phonemes (bands overlap 5/6 -> halve loads).
// Out-of-band extra terms are exp(<-90) == 0 in fp32, so joint accumulation is exact.
__global__ __launch_bounds__(256) void pool_kernel(const float* __restrict__ mels,
                                                   const int* __restrict__ text_mask,
                                                   const float2* __restrict__ packed,
                                                   const int2* __restrict__ bounds,
                                                   float* __restrict__ aligned,
                                                   float* __restrict__ dur) {
    int wid  = (int)((blockIdx.x * blockDim.x + threadIdx.x) >> 6);
    int lane = threadIdx.x & 63;
    if (wid >= B_ * (T1_ / 2)) return;
    int b = wid >> 8, s0 = (wid & 255) * 2;
    float fs0 = (float)s0, fs1 = fs0 + 1.0f;

    const float2* pk   = packed + (size_t)b * T2_;
    const float2* mel2 = (const float2*)(mels + (size_t)b * T2_ * F_);
    int2 b0 = bounds[(size_t)b * T1_ + s0];
    int2 b1 = bounds[(size_t)b * T1_ + s0 + 1];
    int t_lo = b0.x, t_hi = b1.y;       // covers both bands (monotone)

    float ax0 = 0.f, ay0 = 0.f, g0s = 0.f;
    float ax1 = 0.f, ay1 = 0.f, g1s = 0.f;
    int t = t_lo;
    for (; t + 2 <= t_hi; t += 2) {
        float2 p0 = pk[t], p1 = pk[t + 1];
        float2 m0 = mel2[(size_t)t * 64 + lane];
        float2 m1 = mel2[(size_t)(t + 1) * 64 + lane];
        float d00 = p0.x - fs0, d01 = p0.x - fs1;
        float d10 = p1.x - fs0, d11 = p1.x - fs1;
        float g00 = __expf(-DELTA_C * d00 * d00) * p0.y;
        float g01 = __expf(-DELTA_C * d01 * d01) * p0.y;
        float g10 = __expf(-DELTA_C * d10 * d10) * p1.y;
        float g11 = __expf(-DELTA_C * d11 * d11) * p1.y;
        g0s += g00 + g10; g1s += g01 + g11;
        ax0 += g00 * m0.x + g10 * m1.x;  ay0 += g00 * m0.y + g10 * m1.y;
        ax1 += g01 * m0.x + g11 * m1.x;  ay1 += g01 * m0.y + g11 * m1.y;
    }
    for (; t < t_hi; t++) {
        float2 p = pk[t];
        float2 m = mel2[(size_t)t * 64 + lane];
        float d0 = p.x - fs0, d1 = p.x - fs1;
        float ga = __expf(-DELTA_C * d0 * d0) * p.y;
        float gb = __expf(-DELTA_C * d1 * d1) * p.y;
        g0s += ga; g1s += gb;
        ax0 += ga * m.x; ay0 += ga * m.y;
        ax1 += gb * m.x; ay1 += gb * m.y;
    }

    float tm0 = (float)text_mask[(size_t)b * T1_ + s0];
    float tm1 = (float)text_mask[(size_t)b * T1_ + s0 + 1];
    float inv0 = tm0 / (g0s + EPS_C);
    float inv1 = tm1 / (g1s + EPS_C);
    float2 o0 = {ax0 * inv0, ay0 * inv0};
    float2 o1 = {ax1 * inv1, ay1 * inv1};
    ((float2*)(aligned + ((size_t)b * T1_ + s0) * F_))[lane] = o0;
    ((float2*)(aligned + ((size_t)b * T1_ + s0 + 1) * F_))[lane] = o1;
    if (lane == 0) {
        dur[(size_t)b * T1_ + s0]     = g0s * tm0;
        dur[(size_t)b * T1_ + s0 + 1] = g1s * tm1;
    }
}

extern "C" void kernel_launch(void* const* d_in, const int* in_sizes, int n_in,
                              void* d_out, int out_size, void* d_ws, size_t ws_size,
                              hipStream_t stream) {
    const float* mels      = (const float*)d_in[0];
    const float* alpha     = (const float*)d_in[1];
    const int*   mel_mask  = (const int*)d_in[2];
    const int*   text_mask = (const int*)d_in[3];

    float* out     = (float*)d_out;
    float* aligned = out;                                   // B*T1*F
    float* dur     = out + (size_t)B_ * T1_ * F_;           // B*T1
    float* imv     = dur + (size_t)B_ * T1_;                // B*T2

    float*  ws     = (float*)d_ws;                          // 512 KB + 64 KB used
    float*  act    = ws;
    float*  prop   = ws + (size_t)B_ * T2_;
    float2* packed = (float2*)(ws + 2 * (size_t)B_ * T2_);
    int2*   bounds = (int2*)(ws + 4 * (size_t)B_ * T2_);

    dim3 blk(256);
    actprop_kernel<<<(B_ * T2_) / 4, blk, 0, stream>>>(mels, alpha, mel_mask, act, prop);
    scan_kernel   <<<B_,            blk, 0, stream>>>(prop, act, mel_mask, text_mask, imv, packed, bounds);
    pool_kernel   <<<(B_ * T1_ / 2) / 4, blk, 0, stream>>>(mels, text_mask, packed, bounds, aligned, dur);
}